// Round 7
// baseline (356.259 us; speedup 1.0000x reference)
//
#include <hip/hip_runtime.h>
#include <hip/hip_bf16.h>

#define NB 4
#define NC 512
#define NN 4096
#define NM 640
#define LOG2E 1.4426950408889634f

typedef __attribute__((ext_vector_type(8))) short bf16x8;
typedef __attribute__((ext_vector_type(4))) float f32x4;

__device__ __forceinline__ f32x4 mfma16(bf16x8 a, bf16x8 b, f32x4 c) {
  return __builtin_amdgcn_mfma_f32_16x16x32_bf16(a, b, c, 0, 0, 0);
}

__device__ __forceinline__ unsigned short f2bf(float f) {
  unsigned int u = __float_as_uint(f);
  u += 0x7fffu + ((u >> 16) & 1u);   // round-to-nearest-even
  return (unsigned short)(u >> 16);
}

// ---------------- pack weights: W[640][512] bf16 + bias[640] f32 ----------------
__global__ void pack_w(const float* __restrict__ wq, const float* __restrict__ bq,
                       const float* __restrict__ wk, const float* __restrict__ bk,
                       const float* __restrict__ wv, const float* __restrict__ bv,
                       unsigned short* __restrict__ W, float* __restrict__ bias) {
  int idx = blockIdx.x * 256 + threadIdx.x;
  if (idx < NM * NC) {
    int r = idx >> 9, c = idx & (NC - 1);
    float v;
    if (r < 64) v = wq[r * NC + c];
    else if (r < 128) v = wk[(r - 64) * NC + c];
    else v = wv[(r - 128) * NC + c];
    W[idx] = f2bf(v);
  }
  if (idx < NM)
    bias[idx] = (idx < 64) ? bq[idx] : (idx < 128 ? bk[idx - 64] : bv[idx - 128]);
}

// ---------------- transpose + convert: x[b][c][n] f32 -> XT[b][n][c] bf16 ----------------
__global__ void xpose(const float* __restrict__ x, unsigned short* __restrict__ XT) {
  __shared__ float t[64][65];
  int b = blockIdx.z;
  int c0 = blockIdx.y * 64, n0 = blockIdx.x * 64;
  int tx = threadIdx.x & 63, ty = threadIdx.x >> 6;  // 256 threads
  const float* xb = x + (size_t)b * NC * NN;
#pragma unroll
  for (int i = 0; i < 16; ++i) {
    int c = i * 4 + ty;
    t[c][tx] = xb[(size_t)(c0 + c) * NN + n0 + tx];
  }
  __syncthreads();
  unsigned short* xtb = XT + (size_t)b * NN * NC;
#pragma unroll
  for (int i = 0; i < 16; ++i) {
    int n = i * 4 + ty;
    xtb[(size_t)(n0 + n) * NC + c0 + tx] = f2bf(t[tx][n]);
  }
}

// ---------------- QKV projection GEMM (NT): C[m][n] = sum_k W[m][k]*XT[n][k] ----------------
// grid (8, 8, 4) = 256 blocks, 512 threads. Tile: 80 m x 512 n.
// Q rows are pre-scaled by LOG2E so attention works in exp2 domain.
__global__ __launch_bounds__(512) void gemm_qkv(
    const unsigned short* __restrict__ W, const float* __restrict__ bias,
    const unsigned short* __restrict__ XT,
    unsigned short* __restrict__ QT, unsigned short* __restrict__ KT,
    unsigned short* __restrict__ V) {
  int b = blockIdx.z;
  int m0 = blockIdx.y * 80;
  int wave = threadIdx.x >> 6, lane = threadIdx.x & 63;
  int nw = blockIdx.x * 512 + wave * 64;
  int lcol = lane & 15, lkg = lane >> 4;
  const unsigned short* xtb = XT + (size_t)b * NN * NC;
  f32x4 acc[5][4] = {};
  for (int k0 = 0; k0 < NC; k0 += 32) {
    int ko = k0 + lkg * 8;
    bf16x8 afr[5], bfr[4];
#pragma unroll
    for (int i = 0; i < 5; ++i)
      afr[i] = *reinterpret_cast<const bf16x8*>(W + (size_t)(m0 + 16 * i + lcol) * NC + ko);
#pragma unroll
    for (int j = 0; j < 4; ++j)
      bfr[j] = *reinterpret_cast<const bf16x8*>(xtb + (size_t)(nw + 16 * j + lcol) * NC + ko);
#pragma unroll
    for (int i = 0; i < 5; ++i)
#pragma unroll
      for (int j = 0; j < 4; ++j)
        acc[i][j] = mfma16(afr[i], bfr[j], acc[i][j]);
  }
  int rbase = lkg * 4;  // D row = (lane>>4)*4 + r, col = lane&15
#pragma unroll
  for (int i = 0; i < 5; ++i) {
    int mrow = m0 + 16 * i;  // block-uniform subtile base
    if (mrow < 128) {
      // Q or K subtile -> write transposed [n][64] bf16 (Q pre-scaled by LOG2E)
      bool isq = mrow < 64;
      unsigned short* T = isq ? (QT + (size_t)b * NN * 64) : (KT + (size_t)b * NN * 64);
      int mb = mrow & 63;
      float sc = isq ? LOG2E : 1.0f;
#pragma unroll
      for (int j = 0; j < 4; ++j) {
        int n = nw + 16 * j + lcol;
        union { unsigned short h[4]; unsigned long long u; } pk;
#pragma unroll
        for (int r = 0; r < 4; ++r)
          pk.h[r] = f2bf((acc[i][j][r] + bias[mrow + rbase + r]) * sc);
        *reinterpret_cast<unsigned long long*>(T + (size_t)n * 64 + mb + rbase) = pk.u;
      }
    } else {
      // V subtile -> row-major [c][n] bf16
      unsigned short* vb = V + (size_t)b * NC * NN;
#pragma unroll
      for (int r = 0; r < 4; ++r) {
        int m = mrow + rbase + r;
        float bs = bias[m];
        int c = m - 128;
#pragma unroll
        for (int j = 0; j < 4; ++j) {
          int n = nw + 16 * j + lcol;
          vb[(size_t)c * NN + n] = f2bf(acc[i][j][r] + bs);
        }
      }
    }
  }
}

// ---------------- attention stats: exact m_j, l_j per column (log2 domain) ----------------
__global__ __launch_bounds__(512, 2) void attn_stats(
    const unsigned short* __restrict__ QT, const unsigned short* __restrict__ KT,
    float* __restrict__ Mst, float* __restrict__ Lst) {
  int bid = blockIdx.x;
  int b = (bid & 7) >> 1;
  int jb = ((bid >> 3) << 1) | (bid & 1);
  int j0 = jb * 64;
  int wave = threadIdx.x >> 6, lane = threadIdx.x & 63;
  int lcol = lane & 15, lkg = lane >> 4;

  __shared__ float sm[64][9], sl[64][9];

  const unsigned short* qt = QT + (size_t)b * NN * 64;
  const unsigned short* kt = KT + (size_t)b * NN * 64;

  bf16x8 kfr[4][2];
#pragma unroll
  for (int fn = 0; fn < 4; ++fn)
#pragma unroll
    for (int ks = 0; ks < 2; ++ks)
      kfr[fn][ks] = *reinterpret_cast<const bf16x8*>(
          kt + (size_t)(j0 + 16 * fn + lcol) * 64 + ks * 32 + lkg * 8);

  float m_l[4], l_l[4];
#pragma unroll
  for (int fn = 0; fn < 4; ++fn) { m_l[fn] = -1e30f; l_l[fn] = 0.f; }

  bf16x8 qfr[2];
#pragma unroll
  for (int ks = 0; ks < 2; ++ks)
    qfr[ks] = *reinterpret_cast<const bf16x8*>(
        qt + (size_t)(wave * 16 + lcol) * 64 + ks * 32 + lkg * 8);

  for (int it = 0; it < NN / 128; ++it) {
    f32x4 s[4] = {};
#pragma unroll
    for (int ks = 0; ks < 2; ++ks)
#pragma unroll
      for (int fn = 0; fn < 4; ++fn)
        s[fn] = mfma16(qfr[ks], kfr[fn][ks], s[fn]);
    // prefetch next Q strip (consumed next iter; latency hides under stats VALU)
    if (it + 1 < NN / 128) {
      int ib = ((it + 1) * 8 + wave) * 16;
#pragma unroll
      for (int ks = 0; ks < 2; ++ks)
        qfr[ks] = *reinterpret_cast<const bf16x8*>(
            qt + (size_t)(ib + lcol) * 64 + ks * 32 + lkg * 8);
    }
#pragma unroll
    for (int fn = 0; fn < 4; ++fn) {
      float mx = fmaxf(fmaxf(s[fn][0], s[fn][1]), fmaxf(s[fn][2], s[fn][3]));
      float nm = fmaxf(m_l[fn], mx);
      float ps = 0.f;
#pragma unroll
      for (int r = 0; r < 4; ++r) ps += exp2f(s[fn][r] - nm);
      l_l[fn] = l_l[fn] * exp2f(m_l[fn] - nm) + ps;
      m_l[fn] = nm;
    }
  }

  // merge the 4 lkg replicas (lanes differing in bits 4,5)
#pragma unroll
  for (int fn = 0; fn < 4; ++fn) {
#pragma unroll
    for (int off = 16; off <= 32; off <<= 1) {
      float om = __shfl_xor(m_l[fn], off), ol = __shfl_xor(l_l[fn], off);
      float nm = fmaxf(m_l[fn], om);
      l_l[fn] = l_l[fn] * exp2f(m_l[fn] - nm) + ol * exp2f(om - nm);
      m_l[fn] = nm;
    }
    if (lkg == 0) { sm[16 * fn + lcol][wave] = m_l[fn]; sl[16 * fn + lcol][wave] = l_l[fn]; }
  }
  __syncthreads();
  if (wave == 0) {
    int j = lane;  // 0..63
    float m = -1e30f, l = 0.f;
#pragma unroll
    for (int w = 0; w < 8; ++w) {
      float om = sm[j][w], ol = sl[j][w];
      float nm = fmaxf(m, om);
      l = l * exp2f(m - nm) + ol * exp2f(om - nm);
      m = nm;
    }
    Mst[(size_t)b * NN + j0 + j] = m;   // log2-domain max
    Lst[(size_t)b * NN + j0 + j] = l;
  }
}

// ---------------- attention PV: pure GEMM pipeline with known (m,l) ----------------
// grid 512 = (b, jb 0..127) XCD-swizzled, 512 threads, j-tile 32.
// __launch_bounds__(512,4): VGPR<=128 -> 2 blocks/CU -> waves from two INDEPENDENT
// blocks per SIMD (TLP hides V latency + barrier drain; lockstep broken).
__global__ __launch_bounds__(512, 4) void attn_pv(
    const unsigned short* __restrict__ QT, const unsigned short* __restrict__ KT,
    const unsigned short* __restrict__ V, const float* __restrict__ x,
    const float* __restrict__ gamma, const float* __restrict__ Mst,
    const float* __restrict__ Lst, float* __restrict__ out) {
  int bid = blockIdx.x;
  int b = (bid & 7) >> 1;                    // XCD pair {2b,2b+1}
  int jb = ((bid >> 3) << 1) | (bid & 1);    // 0..127
  int j0 = jb * 32;
  int wave = threadIdx.x >> 6, lane = threadIdx.x & 63;
  int lcol = lane & 15, lkg = lane >> 4;

  __shared__ __align__(16) unsigned short plds[2][32 * 128];  // P^T [j][i], dbuf, swizzled

  const unsigned short* qt = QT + (size_t)b * NN * 64;
  const unsigned short* kt = KT + (size_t)b * NN * 64;
  const unsigned short* vp = V + (size_t)b * NC * NN;

  bf16x8 kfr[2][2];
  float mlog[2], lj[2];
#pragma unroll
  for (int fn = 0; fn < 2; ++fn) {
#pragma unroll
    for (int ks = 0; ks < 2; ++ks)
      kfr[fn][ks] = *reinterpret_cast<const bf16x8*>(
          kt + (size_t)(j0 + 16 * fn + lcol) * 64 + ks * 32 + lkg * 8);
    mlog[fn] = Mst[(size_t)b * NN + j0 + 16 * fn + lcol];  // log2-domain
    lj[fn] = Lst[(size_t)b * NN + j0 + 16 * fn + lcol];
  }

  f32x4 oacc[4][2] = {};  // [cm][fn]; wave owns c rows [64*wave, +64)

  for (int it = 0; it < NN / 128; ++it) {
    int i0 = it * 128;
    char* pbuf = reinterpret_cast<char*>(plds[it & 1]);

    // ---- S strip: rows [i0+16*wave, +16) x 32 cols (Q pre-scaled by log2e) ----
    bf16x8 qfr[2];
#pragma unroll
    for (int ks = 0; ks < 2; ++ks)
      qfr[ks] = *reinterpret_cast<const bf16x8*>(
          qt + (size_t)(i0 + 16 * wave + lcol) * 64 + ks * 32 + lkg * 8);
    f32x4 s[2] = {};
#pragma unroll
    for (int ks = 0; ks < 2; ++ks)
#pragma unroll
      for (int fn = 0; fn < 2; ++fn)
        s[fn] = mfma16(qfr[ks], kfr[fn][ks], s[fn]);

    // ---- P = exp2(S - m), pack bf16, write P^T swizzled ----
#pragma unroll
    for (int fn = 0; fn < 2; ++fn) {
      union { unsigned short h[4]; unsigned long long u; } pk;
#pragma unroll
      for (int r = 0; r < 4; ++r)
        pk.h[r] = f2bf(exp2f(s[fn][r] - mlog[fn]));
      int j = 16 * fn + lcol;
      int byteoff = (j * 256 + wave * 32 + lkg * 8) ^ ((j & 7) << 4);
      *reinterpret_cast<unsigned long long*>(pbuf + byteoff) = pk.u;
    }

    // ---- raw barrier: drain LDS writes only ----
    asm volatile("s_waitcnt lgkmcnt(0)" ::: "memory");
    __builtin_amdgcn_s_barrier();
    asm volatile("" ::: "memory");

    // ---- PV: O[64c][32j] += V[c][i-block] * P^T ----
#pragma unroll
    for (int ks = 0; ks < 4; ++ks) {
      bf16x8 pfr[2];
#pragma unroll
      for (int fn = 0; fn < 2; ++fn) {
        int j = 16 * fn + lcol;
        int byteoff = (j * 256 + ks * 64 + lkg * 16) ^ ((j & 7) << 4);
        pfr[fn] = *reinterpret_cast<const bf16x8*>(pbuf + byteoff);
      }
#pragma unroll
      for (int cm = 0; cm < 4; ++cm) {
        bf16x8 vfr = *reinterpret_cast<const bf16x8*>(
            vp + (size_t)(64 * wave + 16 * cm + lcol) * NN + i0 + ks * 32 + lkg * 8);
#pragma unroll
        for (int fn = 0; fn < 2; ++fn)
          oacc[cm][fn] = mfma16(vfr, pfr[fn], oacc[cm][fn]);
      }
    }
  }

  // ---- epilogue: out = gamma * O/l + x ----
  float g = gamma[0];
  const float* xb = x + (size_t)b * NC * NN;
  float* ob = out + (size_t)b * NC * NN;
#pragma unroll
  for (int fn = 0; fn < 2; ++fn) {
    float sc = g / lj[fn];
    int j = j0 + 16 * fn + lcol;
#pragma unroll
    for (int cm = 0; cm < 4; ++cm) {
      int c = 64 * wave + 16 * cm + lkg * 4;
#pragma unroll
      for (int r = 0; r < 4; ++r) {
        size_t idx = (size_t)(c + r) * NN + j;
        ob[idx] = oacc[cm][fn][r] * sc + xb[idx];
      }
    }
  }
}

extern "C" void kernel_launch(void* const* d_in, const int* in_sizes, int n_in,
                              void* d_out, int out_size, void* d_ws, size_t ws_size,
                              hipStream_t stream) {
  const float* x  = (const float*)d_in[0];
  const float* wq = (const float*)d_in[1];
  const float* bq = (const float*)d_in[2];
  const float* wk = (const float*)d_in[3];
  const float* bk = (const float*)d_in[4];
  const float* wv = (const float*)d_in[5];
  const float* bv = (const float*)d_in[6];
  const float* gm = (const float*)d_in[7];
  float* out = (float*)d_out;

  char* ws = (char*)d_ws;
  unsigned short* XT = (unsigned short*)(ws);                             // 16 MB
  unsigned short* Vb = (unsigned short*)(ws + (size_t)16 * 1024 * 1024);  // 16 MB
  unsigned short* QT = (unsigned short*)(ws + (size_t)32 * 1024 * 1024);  // 2 MB
  unsigned short* KT = (unsigned short*)(ws + (size_t)34 * 1024 * 1024);  // 2 MB
  unsigned short* Wp = (unsigned short*)(ws + (size_t)36 * 1024 * 1024);  // 640 KB
  float* biasp = (float*)(ws + (size_t)36 * 1024 * 1024 + 704 * 1024);    // 2.5 KB
  float* Mst   = (float*)(ws + (size_t)36 * 1024 * 1024 + 768 * 1024);    // 64 KB
  float* Lst   = (float*)(ws + (size_t)36 * 1024 * 1024 + 832 * 1024);    // 64 KB

  pack_w<<<(NM * NC + 255) / 256, 256, 0, stream>>>(wq, bq, wk, bk, wv, bv, Wp, biasp);
  xpose<<<dim3(NN / 64, NC / 64, NB), 256, 0, stream>>>(x, XT);
  gemm_qkv<<<dim3(NN / 512, NM / 80, NB), 512, 0, stream>>>(Wp, biasp, XT, QT, KT, Vb);
  attn_stats<<<256, 512, 0, stream>>>(QT, KT, Mst, Lst);
  attn_pv<<<512, 512, 0, stream>>>(QT, KT, Vb, x, gm, Mst, Lst, out);
}

// Round 8
// 297.875 us; speedup vs baseline: 1.1960x; 1.1960x over previous
//
#include <hip/hip_runtime.h>
#include <hip/hip_bf16.h>

#define NB 4
#define NC 512
#define NN 4096
#define NM 640
#define LOG2E 1.4426950408889634f

typedef __attribute__((ext_vector_type(8))) short bf16x8;
typedef __attribute__((ext_vector_type(4))) float f32x4;

__device__ __forceinline__ f32x4 mfma16(bf16x8 a, bf16x8 b, f32x4 c) {
  return __builtin_amdgcn_mfma_f32_16x16x32_bf16(a, b, c, 0, 0, 0);
}

__device__ __forceinline__ unsigned short f2bf(float f) {
  unsigned int u = __float_as_uint(f);
  u += 0x7fffu + ((u >> 16) & 1u);   // round-to-nearest-even
  return (unsigned short)(u >> 16);
}

// ---------------- pack weights: W[640][512] bf16 + bias[640] f32 ----------------
__global__ void pack_w(const float* __restrict__ wq, const float* __restrict__ bq,
                       const float* __restrict__ wk, const float* __restrict__ bk,
                       const float* __restrict__ wv, const float* __restrict__ bv,
                       unsigned short* __restrict__ W, float* __restrict__ bias) {
  int idx = blockIdx.x * 256 + threadIdx.x;
  if (idx < NM * NC) {
    int r = idx >> 9, c = idx & (NC - 1);
    float v;
    if (r < 64) v = wq[r * NC + c];
    else if (r < 128) v = wk[(r - 64) * NC + c];
    else v = wv[(r - 128) * NC + c];
    W[idx] = f2bf(v);
  }
  if (idx < NM)
    bias[idx] = (idx < 64) ? bq[idx] : (idx < 128 ? bk[idx - 64] : bv[idx - 128]);
}

// ---------------- transpose + convert: x[b][c][n] f32 -> XT[b][n][c] bf16 ----------------
__global__ void xpose(const float* __restrict__ x, unsigned short* __restrict__ XT) {
  __shared__ float t[64][65];
  int b = blockIdx.z;
  int c0 = blockIdx.y * 64, n0 = blockIdx.x * 64;
  int tx = threadIdx.x & 63, ty = threadIdx.x >> 6;  // 256 threads
  const float* xb = x + (size_t)b * NC * NN;
#pragma unroll
  for (int i = 0; i < 16; ++i) {
    int c = i * 4 + ty;
    t[c][tx] = xb[(size_t)(c0 + c) * NN + n0 + tx];
  }
  __syncthreads();
  unsigned short* xtb = XT + (size_t)b * NN * NC;
#pragma unroll
  for (int i = 0; i < 16; ++i) {
    int n = i * 4 + ty;
    xtb[(size_t)(n0 + n) * NC + c0 + tx] = f2bf(t[tx][n]);
  }
}

// ---------------- QKV projection GEMM (NT): C[m][n] = sum_k W[m][k]*XT[n][k] ----------------
// grid (8, 8, 4) = 256 blocks, 512 threads. Tile: 80 m x 512 n.
// Q rows are pre-scaled by LOG2E so attention works in exp2 domain.
__global__ __launch_bounds__(512) void gemm_qkv(
    const unsigned short* __restrict__ W, const float* __restrict__ bias,
    const unsigned short* __restrict__ XT,
    unsigned short* __restrict__ QT, unsigned short* __restrict__ KT,
    unsigned short* __restrict__ V) {
  int b = blockIdx.z;
  int m0 = blockIdx.y * 80;
  int wave = threadIdx.x >> 6, lane = threadIdx.x & 63;
  int nw = blockIdx.x * 512 + wave * 64;
  int lcol = lane & 15, lkg = lane >> 4;
  const unsigned short* xtb = XT + (size_t)b * NN * NC;
  f32x4 acc[5][4] = {};
  for (int k0 = 0; k0 < NC; k0 += 32) {
    int ko = k0 + lkg * 8;
    bf16x8 afr[5], bfr[4];
#pragma unroll
    for (int i = 0; i < 5; ++i)
      afr[i] = *reinterpret_cast<const bf16x8*>(W + (size_t)(m0 + 16 * i + lcol) * NC + ko);
#pragma unroll
    for (int j = 0; j < 4; ++j)
      bfr[j] = *reinterpret_cast<const bf16x8*>(xtb + (size_t)(nw + 16 * j + lcol) * NC + ko);
#pragma unroll
    for (int i = 0; i < 5; ++i)
#pragma unroll
      for (int j = 0; j < 4; ++j)
        acc[i][j] = mfma16(afr[i], bfr[j], acc[i][j]);
  }
  int rbase = lkg * 4;  // D row = (lane>>4)*4 + r, col = lane&15
#pragma unroll
  for (int i = 0; i < 5; ++i) {
    int mrow = m0 + 16 * i;  // block-uniform subtile base
    if (mrow < 128) {
      // Q or K subtile -> write transposed [n][64] bf16 (Q pre-scaled by LOG2E)
      bool isq = mrow < 64;
      unsigned short* T = isq ? (QT + (size_t)b * NN * 64) : (KT + (size_t)b * NN * 64);
      int mb = mrow & 63;
      float sc = isq ? LOG2E : 1.0f;
#pragma unroll
      for (int j = 0; j < 4; ++j) {
        int n = nw + 16 * j + lcol;
        union { unsigned short h[4]; unsigned long long u; } pk;
#pragma unroll
        for (int r = 0; r < 4; ++r)
          pk.h[r] = f2bf((acc[i][j][r] + bias[mrow + rbase + r]) * sc);
        *reinterpret_cast<unsigned long long*>(T + (size_t)n * 64 + mb + rbase) = pk.u;
      }
    } else {
      // V subtile -> row-major [c][n] bf16
      unsigned short* vb = V + (size_t)b * NC * NN;
#pragma unroll
      for (int r = 0; r < 4; ++r) {
        int m = mrow + rbase + r;
        float bs = bias[m];
        int c = m - 128;
#pragma unroll
        for (int j = 0; j < 4; ++j) {
          int n = nw + 16 * j + lcol;
          vb[(size_t)c * NN + n] = f2bf(acc[i][j][r] + bs);
        }
      }
    }
  }
}

// ---------------- attention stats: exact m_j, l_j per column (log2 domain) ----------------
__global__ __launch_bounds__(512, 2) void attn_stats(
    const unsigned short* __restrict__ QT, const unsigned short* __restrict__ KT,
    float* __restrict__ Mst, float* __restrict__ Lst) {
  int bid = blockIdx.x;
  int b = (bid & 7) >> 1;
  int jb = ((bid >> 3) << 1) | (bid & 1);
  int j0 = jb * 64;
  int wave = threadIdx.x >> 6, lane = threadIdx.x & 63;
  int lcol = lane & 15, lkg = lane >> 4;

  __shared__ float sm[64][9], sl[64][9];

  const unsigned short* qt = QT + (size_t)b * NN * 64;
  const unsigned short* kt = KT + (size_t)b * NN * 64;

  bf16x8 kfr[4][2];
#pragma unroll
  for (int fn = 0; fn < 4; ++fn)
#pragma unroll
    for (int ks = 0; ks < 2; ++ks)
      kfr[fn][ks] = *reinterpret_cast<const bf16x8*>(
          kt + (size_t)(j0 + 16 * fn + lcol) * 64 + ks * 32 + lkg * 8);

  float m_l[4], l_l[4];
#pragma unroll
  for (int fn = 0; fn < 4; ++fn) { m_l[fn] = -1e30f; l_l[fn] = 0.f; }

  bf16x8 qfr[2];
#pragma unroll
  for (int ks = 0; ks < 2; ++ks)
    qfr[ks] = *reinterpret_cast<const bf16x8*>(
        qt + (size_t)(wave * 16 + lcol) * 64 + ks * 32 + lkg * 8);

  for (int it = 0; it < NN / 128; ++it) {
    f32x4 s[4] = {};
#pragma unroll
    for (int ks = 0; ks < 2; ++ks)
#pragma unroll
      for (int fn = 0; fn < 4; ++fn)
        s[fn] = mfma16(qfr[ks], kfr[fn][ks], s[fn]);
    // prefetch next Q strip (consumed next iter; latency hides under stats VALU)
    if (it + 1 < NN / 128) {
      int ib = ((it + 1) * 8 + wave) * 16;
#pragma unroll
      for (int ks = 0; ks < 2; ++ks)
        qfr[ks] = *reinterpret_cast<const bf16x8*>(
            qt + (size_t)(ib + lcol) * 64 + ks * 32 + lkg * 8);
    }
#pragma unroll
    for (int fn = 0; fn < 4; ++fn) {
      float mx = fmaxf(fmaxf(s[fn][0], s[fn][1]), fmaxf(s[fn][2], s[fn][3]));
      float nm = fmaxf(m_l[fn], mx);
      float ps = 0.f;
#pragma unroll
      for (int r = 0; r < 4; ++r) ps += exp2f(s[fn][r] - nm);
      l_l[fn] = l_l[fn] * exp2f(m_l[fn] - nm) + ps;
      m_l[fn] = nm;
    }
  }

  // merge the 4 lkg replicas (lanes differing in bits 4,5)
#pragma unroll
  for (int fn = 0; fn < 4; ++fn) {
#pragma unroll
    for (int off = 16; off <= 32; off <<= 1) {
      float om = __shfl_xor(m_l[fn], off), ol = __shfl_xor(l_l[fn], off);
      float nm = fmaxf(m_l[fn], om);
      l_l[fn] = l_l[fn] * exp2f(m_l[fn] - nm) + ol * exp2f(om - nm);
      m_l[fn] = nm;
    }
    if (lkg == 0) { sm[16 * fn + lcol][wave] = m_l[fn]; sl[16 * fn + lcol][wave] = l_l[fn]; }
  }
  __syncthreads();
  if (wave == 0) {
    int j = lane;  // 0..63
    float m = -1e30f, l = 0.f;
#pragma unroll
    for (int w = 0; w < 8; ++w) {
      float om = sm[j][w], ol = sl[j][w];
      float nm = fmaxf(m, om);
      l = l * exp2f(m - nm) + ol * exp2f(om - nm);
      m = nm;
    }
    Mst[(size_t)b * NN + j0 + j] = m;   // log2-domain max
    Lst[(size_t)b * NN + j0 + j] = l;
  }
}

// ---------------- attention PV: c-split for cross-block TLP ----------------
// grid 512 = 4b x 64jb x 2 c-halves; 256 threads (4 waves). Wave owns 64c x 64j.
// Each block reads only its 2 MB V half -> total V traffic unchanged vs R3.
// 2-3 independent blocks/CU: one block's PV covers another's barrier/V-wait.
__global__ __launch_bounds__(256, 2) void attn_pv(
    const unsigned short* __restrict__ QT, const unsigned short* __restrict__ KT,
    const unsigned short* __restrict__ V, const float* __restrict__ x,
    const float* __restrict__ gamma, const float* __restrict__ Mst,
    const float* __restrict__ Lst, float* __restrict__ out) {
  int bid = blockIdx.x;
  int b = (bid & 7) >> 1;        // batch -> XCD pair {2b,2b+1}
  int ch = bid & 1;              // c-half (XCD-uniform: only its 2 MB of V in L2)
  int jb = bid >> 3;             // 0..63
  int j0 = jb * 64;
  int c0 = ch * 256;
  int wave = threadIdx.x >> 6, lane = threadIdx.x & 63;
  int lcol = lane & 15, lkg = lane >> 4;

  __shared__ __align__(16) unsigned short plds[2][64 * 64];  // P^T [j][i] dbuf, swizzled

  const unsigned short* qt = QT + (size_t)b * NN * 64;
  const unsigned short* kt = KT + (size_t)b * NN * 64;
  const unsigned short* vp = V + (size_t)b * NC * NN;

  bf16x8 kfr[4][2];
  float mlog[4], lj[4];
#pragma unroll
  for (int fn = 0; fn < 4; ++fn) {
#pragma unroll
    for (int ks = 0; ks < 2; ++ks)
      kfr[fn][ks] = *reinterpret_cast<const bf16x8*>(
          kt + (size_t)(j0 + 16 * fn + lcol) * 64 + ks * 32 + lkg * 8);
    mlog[fn] = Mst[(size_t)b * NN + j0 + 16 * fn + lcol];  // log2-domain
    lj[fn] = Lst[(size_t)b * NN + j0 + 16 * fn + lcol];
  }

  f32x4 oacc[4][4] = {};  // [cm][fn]; wave owns c rows [c0+64*wave, +64)

  for (int it = 0; it < NN / 64; ++it) {
    int i0 = it * 64;
    char* pbuf = reinterpret_cast<char*>(plds[it & 1]);

    // ---- S strip: rows [i0+16*wave, +16) x 64 cols (Q pre-scaled by log2e) ----
    bf16x8 qfr[2];
#pragma unroll
    for (int ks = 0; ks < 2; ++ks)
      qfr[ks] = *reinterpret_cast<const bf16x8*>(
          qt + (size_t)(i0 + 16 * wave + lcol) * 64 + ks * 32 + lkg * 8);
    f32x4 s[4] = {};
#pragma unroll
    for (int ks = 0; ks < 2; ++ks)
#pragma unroll
      for (int fn = 0; fn < 4; ++fn)
        s[fn] = mfma16(qfr[ks], kfr[fn][ks], s[fn]);

    // ---- P = exp2(S - m), pack bf16, write P^T swizzled (row stride 128B) ----
#pragma unroll
    for (int fn = 0; fn < 4; ++fn) {
      union { unsigned short h[4]; unsigned long long u; } pk;
#pragma unroll
      for (int r = 0; r < 4; ++r)
        pk.h[r] = f2bf(exp2f(s[fn][r] - mlog[fn]));
      int j = 16 * fn + lcol;
      int byteoff = (j * 128 + wave * 32 + lkg * 8) ^ ((j & 7) << 4);
      *reinterpret_cast<unsigned long long*>(pbuf + byteoff) = pk.u;
    }

    // ---- raw barrier: drain LDS writes only ----
    asm volatile("s_waitcnt lgkmcnt(0)" ::: "memory");
    __builtin_amdgcn_s_barrier();
    asm volatile("" ::: "memory");

    // ---- PV: O[64c][64j] += V[c-half][i-block] * P^T ----
#pragma unroll
    for (int ks = 0; ks < 2; ++ks) {
      bf16x8 pfr[4];
#pragma unroll
      for (int fn = 0; fn < 4; ++fn) {
        int j = 16 * fn + lcol;
        int byteoff = (j * 128 + ks * 64 + lkg * 16) ^ ((j & 7) << 4);
        pfr[fn] = *reinterpret_cast<const bf16x8*>(pbuf + byteoff);
      }
#pragma unroll
      for (int cm = 0; cm < 4; ++cm) {
        bf16x8 vfr = *reinterpret_cast<const bf16x8*>(
            vp + (size_t)(c0 + 64 * wave + 16 * cm + lcol) * NN + i0 + ks * 32 + lkg * 8);
#pragma unroll
        for (int fn = 0; fn < 4; ++fn)
          oacc[cm][fn] = mfma16(vfr, pfr[fn], oacc[cm][fn]);
      }
    }
  }

  // ---- epilogue: out = gamma * O/l + x ----
  float g = gamma[0];
  const float* xb = x + (size_t)b * NC * NN;
  float* ob = out + (size_t)b * NC * NN;
#pragma unroll
  for (int fn = 0; fn < 4; ++fn) {
    float sc = g / lj[fn];
    int j = j0 + 16 * fn + lcol;
#pragma unroll
    for (int cm = 0; cm < 4; ++cm) {
      int c = c0 + 64 * wave + 16 * cm + lkg * 4;
#pragma unroll
      for (int r = 0; r < 4; ++r) {
        size_t idx = (size_t)(c + r) * NN + j;
        ob[idx] = oacc[cm][fn][r] * sc + xb[idx];
      }
    }
  }
}

extern "C" void kernel_launch(void* const* d_in, const int* in_sizes, int n_in,
                              void* d_out, int out_size, void* d_ws, size_t ws_size,
                              hipStream_t stream) {
  const float* x  = (const float*)d_in[0];
  const float* wq = (const float*)d_in[1];
  const float* bq = (const float*)d_in[2];
  const float* wk = (const float*)d_in[3];
  const float* bk = (const float*)d_in[4];
  const float* wv = (const float*)d_in[5];
  const float* bv = (const float*)d_in[6];
  const float* gm = (const float*)d_in[7];
  float* out = (float*)d_out;

  char* ws = (char*)d_ws;
  unsigned short* XT = (unsigned short*)(ws);                             // 16 MB
  unsigned short* Vb = (unsigned short*)(ws + (size_t)16 * 1024 * 1024);  // 16 MB
  unsigned short* QT = (unsigned short*)(ws + (size_t)32 * 1024 * 1024);  // 2 MB
  unsigned short* KT = (unsigned short*)(ws + (size_t)34 * 1024 * 1024);  // 2 MB
  unsigned short* Wp = (unsigned short*)(ws + (size_t)36 * 1024 * 1024);  // 640 KB
  float* biasp = (float*)(ws + (size_t)36 * 1024 * 1024 + 704 * 1024);    // 2.5 KB
  float* Mst   = (float*)(ws + (size_t)36 * 1024 * 1024 + 768 * 1024);    // 64 KB
  float* Lst   = (float*)(ws + (size_t)36 * 1024 * 1024 + 832 * 1024);    // 64 KB

  pack_w<<<(NM * NC + 255) / 256, 256, 0, stream>>>(wq, bq, wk, bk, wv, bv, Wp, biasp);
  xpose<<<dim3(NN / 64, NC / 64, NB), 256, 0, stream>>>(x, XT);
  gemm_qkv<<<dim3(NN / 512, NM / 80, NB), 512, 0, stream>>>(Wp, biasp, XT, QT, KT, Vb);
  attn_stats<<<256, 512, 0, stream>>>(QT, KT, Mst, Lst);
  attn_pv<<<512, 256, 0, stream>>>(QT, KT, Vb, x, gm, Mst, Lst, out);
}

// Round 9
// 195.960 us; speedup vs baseline: 1.8180x; 1.5201x over previous
//
#include <hip/hip_runtime.h>
#include <hip/hip_bf16.h>

#define NB 4
#define NC 512
#define NN 4096
#define NM 640
#define IB 64            // i-block per iteration
#define NT (NN / IB)     // 64 iterations
#define LOG2E 1.4426950408889634f

typedef __attribute__((ext_vector_type(8))) short bf16x8;
typedef __attribute__((ext_vector_type(4))) float f32x4;

__device__ __forceinline__ f32x4 mfma16(bf16x8 a, bf16x8 b, f32x4 c) {
  return __builtin_amdgcn_mfma_f32_16x16x32_bf16(a, b, c, 0, 0, 0);
}

__device__ __forceinline__ unsigned short f2bf(float f) {
  unsigned int u = __float_as_uint(f);
  u += 0x7fffu + ((u >> 16) & 1u);   // round-to-nearest-even
  return (unsigned short)(u >> 16);
}

typedef const __attribute__((address_space(1))) char gchar_t;
typedef __attribute__((address_space(3))) char lchar_t;

// ---------------- pack weights: W[640][512] bf16 + bias[640] f32 ----------------
__global__ void pack_w(const float* __restrict__ wq, const float* __restrict__ bq,
                       const float* __restrict__ wk, const float* __restrict__ bk,
                       const float* __restrict__ wv, const float* __restrict__ bv,
                       unsigned short* __restrict__ W, float* __restrict__ bias) {
  int idx = blockIdx.x * 256 + threadIdx.x;
  if (idx < NM * NC) {
    int r = idx >> 9, c = idx & (NC - 1);
    float v;
    if (r < 64) v = wq[r * NC + c];
    else if (r < 128) v = wk[(r - 64) * NC + c];
    else v = wv[(r - 128) * NC + c];
    W[idx] = f2bf(v);
  }
  if (idx < NM)
    bias[idx] = (idx < 64) ? bq[idx] : (idx < 128 ? bk[idx - 64] : bv[idx - 128]);
}

// ---------------- transpose + convert: x[b][c][n] f32 -> XT[b][n][c] bf16 ----------------
__global__ void xpose(const float* __restrict__ x, unsigned short* __restrict__ XT) {
  __shared__ float t[64][65];
  int b = blockIdx.z;
  int c0 = blockIdx.y * 64, n0 = blockIdx.x * 64;
  int tx = threadIdx.x & 63, ty = threadIdx.x >> 6;  // 256 threads
  const float* xb = x + (size_t)b * NC * NN;
#pragma unroll
  for (int i = 0; i < 16; ++i) {
    int c = i * 4 + ty;
    t[c][tx] = xb[(size_t)(c0 + c) * NN + n0 + tx];
  }
  __syncthreads();
  unsigned short* xtb = XT + (size_t)b * NN * NC;
#pragma unroll
  for (int i = 0; i < 16; ++i) {
    int n = i * 4 + ty;
    xtb[(size_t)(n0 + n) * NC + c0 + tx] = f2bf(t[tx][n]);
  }
}

// ---------------- QKV projection GEMM (NT): C[m][n] = sum_k W[m][k]*XT[n][k] ----------------
__global__ __launch_bounds__(512) void gemm_qkv(
    const unsigned short* __restrict__ W, const float* __restrict__ bias,
    const unsigned short* __restrict__ XT,
    unsigned short* __restrict__ QT, unsigned short* __restrict__ KT,
    unsigned short* __restrict__ V) {
  int b = blockIdx.z;
  int m0 = blockIdx.y * 80;
  int wave = threadIdx.x >> 6, lane = threadIdx.x & 63;
  int nw = blockIdx.x * 512 + wave * 64;
  int lcol = lane & 15, lkg = lane >> 4;
  const unsigned short* xtb = XT + (size_t)b * NN * NC;
  f32x4 acc[5][4] = {};
  for (int k0 = 0; k0 < NC; k0 += 32) {
    int ko = k0 + lkg * 8;
    bf16x8 afr[5], bfr[4];
#pragma unroll
    for (int i = 0; i < 5; ++i)
      afr[i] = *reinterpret_cast<const bf16x8*>(W + (size_t)(m0 + 16 * i + lcol) * NC + ko);
#pragma unroll
    for (int j = 0; j < 4; ++j)
      bfr[j] = *reinterpret_cast<const bf16x8*>(xtb + (size_t)(nw + 16 * j + lcol) * NC + ko);
#pragma unroll
    for (int i = 0; i < 5; ++i)
#pragma unroll
      for (int j = 0; j < 4; ++j)
        acc[i][j] = mfma16(afr[i], bfr[j], acc[i][j]);
  }
  int rbase = lkg * 4;  // D row = (lane>>4)*4 + r, col = lane&15
#pragma unroll
  for (int i = 0; i < 5; ++i) {
    int mrow = m0 + 16 * i;  // block-uniform subtile base
    if (mrow < 128) {
      bool isq = mrow < 64;
      unsigned short* T = isq ? (QT + (size_t)b * NN * 64) : (KT + (size_t)b * NN * 64);
      int mb = mrow & 63;
      float sc = isq ? LOG2E : 1.0f;
#pragma unroll
      for (int j = 0; j < 4; ++j) {
        int n = nw + 16 * j + lcol;
        union { unsigned short h[4]; unsigned long long u; } pk;
#pragma unroll
        for (int r = 0; r < 4; ++r)
          pk.h[r] = f2bf((acc[i][j][r] + bias[mrow + rbase + r]) * sc);
        *reinterpret_cast<unsigned long long*>(T + (size_t)n * 64 + mb + rbase) = pk.u;
      }
    } else {
      unsigned short* vb = V + (size_t)b * NC * NN;
#pragma unroll
      for (int r = 0; r < 4; ++r) {
        int m = mrow + rbase + r;
        float bs = bias[m];
        int c = m - 128;
#pragma unroll
        for (int j = 0; j < 4; ++j) {
          int n = nw + 16 * j + lcol;
          vb[(size_t)c * NN + n] = f2bf(acc[i][j][r] + bs);
        }
      }
    }
  }
}

// ---------------- attention stats: exact m_j, l_j per column (log2 domain) ----------------
__global__ __launch_bounds__(512, 2) void attn_stats(
    const unsigned short* __restrict__ QT, const unsigned short* __restrict__ KT,
    float* __restrict__ Mst, float* __restrict__ Lst) {
  int bid = blockIdx.x;
  int b = (bid & 7) >> 1;
  int jb = ((bid >> 3) << 1) | (bid & 1);
  int j0 = jb * 64;
  int wave = threadIdx.x >> 6, lane = threadIdx.x & 63;
  int lcol = lane & 15, lkg = lane >> 4;

  __shared__ float sm[64][9], sl[64][9];

  const unsigned short* qt = QT + (size_t)b * NN * 64;
  const unsigned short* kt = KT + (size_t)b * NN * 64;

  bf16x8 kfr[4][2];
#pragma unroll
  for (int fn = 0; fn < 4; ++fn)
#pragma unroll
    for (int ks = 0; ks < 2; ++ks)
      kfr[fn][ks] = *reinterpret_cast<const bf16x8*>(
          kt + (size_t)(j0 + 16 * fn + lcol) * 64 + ks * 32 + lkg * 8);

  float m_l[4], l_l[4];
#pragma unroll
  for (int fn = 0; fn < 4; ++fn) { m_l[fn] = -1e30f; l_l[fn] = 0.f; }

  bf16x8 qfr[2];
#pragma unroll
  for (int ks = 0; ks < 2; ++ks)
    qfr[ks] = *reinterpret_cast<const bf16x8*>(
        qt + (size_t)(wave * 16 + lcol) * 64 + ks * 32 + lkg * 8);

  for (int it = 0; it < NN / 128; ++it) {
    f32x4 s[4] = {};
#pragma unroll
    for (int ks = 0; ks < 2; ++ks)
#pragma unroll
      for (int fn = 0; fn < 4; ++fn)
        s[fn] = mfma16(qfr[ks], kfr[fn][ks], s[fn]);
    if (it + 1 < NN / 128) {
      int ib = ((it + 1) * 8 + wave) * 16;
#pragma unroll
      for (int ks = 0; ks < 2; ++ks)
        qfr[ks] = *reinterpret_cast<const bf16x8*>(
            qt + (size_t)(ib + lcol) * 64 + ks * 32 + lkg * 8);
    }
#pragma unroll
    for (int fn = 0; fn < 4; ++fn) {
      float mx = fmaxf(fmaxf(s[fn][0], s[fn][1]), fmaxf(s[fn][2], s[fn][3]));
      float nm = fmaxf(m_l[fn], mx);
      float ps = 0.f;
#pragma unroll
      for (int r = 0; r < 4; ++r) ps += exp2f(s[fn][r] - nm);
      l_l[fn] = l_l[fn] * exp2f(m_l[fn] - nm) + ps;
      m_l[fn] = nm;
    }
  }

#pragma unroll
  for (int fn = 0; fn < 4; ++fn) {
#pragma unroll
    for (int off = 16; off <= 32; off <<= 1) {
      float om = __shfl_xor(m_l[fn], off), ol = __shfl_xor(l_l[fn], off);
      float nm = fmaxf(m_l[fn], om);
      l_l[fn] = l_l[fn] * exp2f(m_l[fn] - nm) + ol * exp2f(om - nm);
      m_l[fn] = nm;
    }
    if (lkg == 0) { sm[16 * fn + lcol][wave] = m_l[fn]; sl[16 * fn + lcol][wave] = l_l[fn]; }
  }
  __syncthreads();
  if (wave == 0) {
    int j = lane;
    float m = -1e30f, l = 0.f;
#pragma unroll
    for (int w = 0; w < 8; ++w) {
      float om = sm[j][w], ol = sl[j][w];
      float nm = fmaxf(m, om);
      l = l * exp2f(m - nm) + ol * exp2f(om - nm);
      m = nm;
    }
    Mst[(size_t)b * NN + j0 + j] = m;
    Lst[(size_t)b * NN + j0 + j] = l;
  }
}

// ---------------- attention PV: V via global_load_lds, counted vmcnt pipeline ----------
// grid 256 = (b XCD-pair, jb), 512 threads, 8 waves. Wave w owns c rows [64w,64w+64).
// Per iter: stage V(t+1)->LDS (8x16B gload_lds/wave, own rows), QK^T from regs,
// P^T->LDS; ONE raw barrier with vmcnt(10) (stage(t+1)+Q(t+1) stay in flight);
// PV reads V+P from LDS (ds_read_b128, XOR-swizzled V via pre-swizzled source).
__global__ __launch_bounds__(512, 2) void attn_pv(
    const unsigned short* __restrict__ QT, const unsigned short* __restrict__ KT,
    const unsigned short* __restrict__ V, const float* __restrict__ x,
    const float* __restrict__ gamma, const float* __restrict__ Mst,
    const float* __restrict__ Lst, float* __restrict__ out) {
  int bid = blockIdx.x;
  int b = (bid & 7) >> 1;
  int jb = ((bid >> 3) << 1) | (bid & 1);
  int j0 = jb * 64;
  int wave = threadIdx.x >> 6, lane = threadIdx.x & 63;
  int lcol = lane & 15, lkg = lane >> 4;
  int sw = wave >> 1;    // i-strip 0..3
  int fnh = wave & 1;    // fn half: this wave computes fn = 2*fnh + {0,1}

  __shared__ __align__(16) unsigned short vlds[2][512 * IB];  // 128 KB, V dbuf
  __shared__ __align__(16) unsigned short plds[2][64 * IB];   //  16 KB, P^T dbuf

  const unsigned short* qt = QT + (size_t)b * NN * 64;
  const unsigned short* kt = KT + (size_t)b * NN * 64;
  const unsigned short* vp = V + (size_t)b * NC * NN;

  // staging geometry: lane -> (row within 8-row group, swizzled 16B unit)
  const int lrow = lane >> 3;                       // 0..7
  const int lswz = ((lane & 7) ^ lrow) << 3;        // element offset (units swizzled by row&7)
  lchar_t* vbase = (lchar_t*)vlds;

  auto stage = [&](int itv) {
    int i0 = (itv & (NT - 1)) * IB;
    lchar_t* lb = vbase + (size_t)(itv & 1) * (512 * IB * 2) + wave * (64 * IB * 2);
#pragma unroll
    for (int q = 0; q < 8; ++q) {
      const unsigned short* gp = vp + (size_t)(wave * 64 + q * 8 + lrow) * NN + i0 + lswz;
      __builtin_amdgcn_global_load_lds((gchar_t*)gp, lb + q * 1024, 16, 0, 0);
    }
  };

  // K fragments + stats for this wave's fn pair; l for all 4 fn (epilogue)
  bf16x8 kfr[2][2];
  float ml2[2], lj[4];
#pragma unroll
  for (int f = 0; f < 2; ++f) {
    int fn = 2 * fnh + f;
#pragma unroll
    for (int ks = 0; ks < 2; ++ks)
      kfr[f][ks] = *reinterpret_cast<const bf16x8*>(
          kt + (size_t)(j0 + 16 * fn + lcol) * 64 + ks * 32 + lkg * 8);
    ml2[f] = Mst[(size_t)b * NN + j0 + 16 * fn + lcol];
  }
#pragma unroll
  for (int fn = 0; fn < 4; ++fn)
    lj[fn] = Lst[(size_t)b * NN + j0 + 16 * fn + lcol];

  f32x4 oacc[4][4] = {};  // [cm][fn]

  // prologue: stage V(0), load Q(0)
  stage(0);
  bf16x8 qA[2], qB[2];
  {
    int row = sw * 16 + lcol;
    qA[0] = *reinterpret_cast<const bf16x8*>(qt + (size_t)row * 64 + lkg * 8);
    qA[1] = *reinterpret_cast<const bf16x8*>(qt + (size_t)row * 64 + 32 + lkg * 8);
  }

#define PV_ITER(IT, QC, QN)                                                       \
  {                                                                               \
    const int it_ = (IT);                                                         \
    stage(it_ + 1);                                                               \
    f32x4 s[2] = {};                                                              \
    _Pragma("unroll") for (int ks = 0; ks < 2; ++ks)                              \
      _Pragma("unroll") for (int f = 0; f < 2; ++f)                               \
        s[f] = mfma16(QC[ks], kfr[f][ks], s[f]);                                  \
    {                                                                             \
      int row = ((it_ + 1) & (NT - 1)) * IB + sw * 16 + lcol;                     \
      QN[0] = *reinterpret_cast<const bf16x8*>(qt + (size_t)row * 64 + lkg * 8);  \
      QN[1] = *reinterpret_cast<const bf16x8*>(qt + (size_t)row * 64 + 32 + lkg * 8); \
    }                                                                             \
    char* pb = (char*)plds[it_ & 1];                                              \
    _Pragma("unroll") for (int f = 0; f < 2; ++f) {                               \
      int j = 16 * (2 * fnh + f) + lcol;                                          \
      union { unsigned short h[4]; unsigned long long u; } pk;                    \
      _Pragma("unroll") for (int r = 0; r < 4; ++r)                               \
        pk.h[r] = f2bf(exp2f(s[f][r] - ml2[f]));                                  \
      int bo = (j * 128 + sw * 32 + lkg * 8) ^ ((j & 7) << 4);                    \
      *reinterpret_cast<unsigned long long*>(pb + bo) = pk.u;                     \
    }                                                                             \
    asm volatile("s_waitcnt vmcnt(10) lgkmcnt(0)" ::: "memory");                  \
    __builtin_amdgcn_s_barrier();                                                 \
    asm volatile("" ::: "memory");                                                \
    const char* vb = (const char*)vlds[it_ & 1];                                  \
    __builtin_amdgcn_s_setprio(1);                                                \
    _Pragma("unroll") for (int ks = 0; ks < 2; ++ks) {                            \
      bf16x8 pfr[4];                                                              \
      _Pragma("unroll") for (int fn = 0; fn < 4; ++fn) {                          \
        int j = 16 * fn + lcol;                                                   \
        int bo = (j * 128 + ks * 64 + lkg * 16) ^ ((j & 7) << 4);                 \
        pfr[fn] = *reinterpret_cast<const bf16x8*>(pb + bo);                      \
      }                                                                           \
      _Pragma("unroll") for (int cm = 0; cm < 4; ++cm) {                          \
        int cr = 64 * wave + 16 * cm + lcol;                                      \
        int u = (ks * 4 + lkg) ^ (cr & 7);                                        \
        bf16x8 vfr = *reinterpret_cast<const bf16x8*>(vb + cr * 128 + u * 16);    \
        _Pragma("unroll") for (int fn = 0; fn < 4; ++fn)                          \
          oacc[cm][fn] = mfma16(vfr, pfr[fn], oacc[cm][fn]);                      \
      }                                                                           \
    }                                                                             \
    __builtin_amdgcn_s_setprio(0);                                                \
  }

  for (int it2 = 0; it2 < NT; it2 += 2) {
    PV_ITER(it2 + 0, qA, qB);
    PV_ITER(it2 + 1, qB, qA);
  }
#undef PV_ITER

  // ---- epilogue: out = gamma * O/l + x ----
  float g = gamma[0];
  const float* xb = x + (size_t)b * NC * NN;
  float* ob = out + (size_t)b * NC * NN;
#pragma unroll
  for (int fn = 0; fn < 4; ++fn) {
    float sc = g / lj[fn];
    int j = j0 + 16 * fn + lcol;
#pragma unroll
    for (int cm = 0; cm < 4; ++cm) {
      int c = 64 * wave + 16 * cm + lkg * 4;
#pragma unroll
      for (int r = 0; r < 4; ++r) {
        size_t idx = (size_t)(c + r) * NN + j;
        ob[idx] = oacc[cm][fn][r] * sc + xb[idx];
      }
    }
  }
}

extern "C" void kernel_launch(void* const* d_in, const int* in_sizes, int n_in,
                              void* d_out, int out_size, void* d_ws, size_t ws_size,
                              hipStream_t stream) {
  const float* x  = (const float*)d_in[0];
  const float* wq = (const float*)d_in[1];
  const float* bq = (const float*)d_in[2];
  const float* wk = (const float*)d_in[3];
  const float* bk = (const float*)d_in[4];
  const float* wv = (const float*)d_in[5];
  const float* bv = (const float*)d_in[6];
  const float* gm = (const float*)d_in[7];
  float* out = (float*)d_out;

  char* ws = (char*)d_ws;
  unsigned short* XT = (unsigned short*)(ws);                             // 16 MB
  unsigned short* Vb = (unsigned short*)(ws + (size_t)16 * 1024 * 1024);  // 16 MB
  unsigned short* QT = (unsigned short*)(ws + (size_t)32 * 1024 * 1024);  // 2 MB
  unsigned short* KT = (unsigned short*)(ws + (size_t)34 * 1024 * 1024);  // 2 MB
  unsigned short* Wp = (unsigned short*)(ws + (size_t)36 * 1024 * 1024);  // 640 KB
  float* biasp = (float*)(ws + (size_t)36 * 1024 * 1024 + 704 * 1024);    // 2.5 KB
  float* Mst   = (float*)(ws + (size_t)36 * 1024 * 1024 + 768 * 1024);    // 64 KB
  float* Lst   = (float*)(ws + (size_t)36 * 1024 * 1024 + 832 * 1024);    // 64 KB

  pack_w<<<(NM * NC + 255) / 256, 256, 0, stream>>>(wq, bq, wk, bk, wv, bv, Wp, biasp);
  xpose<<<dim3(NN / 64, NC / 64, NB), 256, 0, stream>>>(x, XT);
  gemm_qkv<<<dim3(NN / 512, NM / 80, NB), 512, 0, stream>>>(Wp, biasp, XT, QT, KT, Vb);
  attn_stats<<<256, 512, 0, stream>>>(QT, KT, Mst, Lst);
  attn_pv<<<256, 512, 0, stream>>>(QT, KT, Vb, x, gm, Mst, Lst, out);
}